// Round 3
// baseline (587.944 us; speedup 1.0000x reference)
//
#include <hip/hip_runtime.h>
#include <stdint.h>
#include <stddef.h>

// Problem constants (fixed by reference)
#define NB 32
#define NN 8192
#define NH 512
#define NE 10
#define HEPS 1e-5f
#define HSLOPE 0.2f

typedef short short8 __attribute__((ext_vector_type(8)));
typedef float f32x4 __attribute__((ext_vector_type(4)));

static __device__ __forceinline__ unsigned short f2bf(float f){
  unsigned u = __float_as_uint(f);
  u += 0x7FFFu + ((u >> 16) & 1u);   // RNE
  return (unsigned short)(u >> 16);
}
static __device__ __forceinline__ float bf2f(unsigned short h){
  return __uint_as_float(((unsigned)h) << 16);
}

// ---------------------------------------------------------------------------
// Prep: W2 [E][512][256] f32 -> bf16 k-major fragment image in ws.
// Layout: [e][kc(8)][sub(2)][col(256)][kslot(4)][kk(8)] halfwords, so a wave's
// B-fragment (col = n*16 + lane&15, k = kc*64+sub*32+(lane>>4)*8+kk) is ONE
// fully-coalesced global_load_dwordx4 (64 lanes x 16B = contiguous 1KB).
// ---------------------------------------------------------------------------
__global__ __launch_bounds__(256) void prep_w2(const float* __restrict__ W2,
                                               unsigned short* __restrict__ ws){
  int idx = blockIdx.x * 256 + threadIdx.x;   // e*131072 + k*256 + col (coalesced read)
  int col = idx & 255;
  int k   = (idx >> 8) & 511;
  int e   = idx >> 17;
  int kc = k >> 6, sub = (k >> 5) & 1, kslot = (k >> 3) & 3, kk = k & 7;
  ws[(((size_t)(e * 8 + kc) * 2 + sub) << 13) + (col << 5) + (kslot << 3) + kk]
      = f2bf(W2[idx]);
}

// ---------------------------------------------------------------------------
// Fused kernel: one block = 64 points, 8 waves (512 thr), 2 blocks/CU.
//   Phase A : layer1 fp32 (8 thr/point, h in regs) -> LN1 -> lrelu -> bf16 LDS
//   GEMM    : 64x256 = A(64x512 LDS) x W2(512x256, direct L2->reg loads),
//             mfma 16x16x32, barrier-free K-loop, 2-deep B prefetch,
//             wave w owns cols [32w, 32w+32)
//   Epilog  : +b2 -> fp32 h2 LDS overlay -> vectorized LN2+lrelu+layer3 -> out
// LDS = max(64KB h1, 74.75KB h2) -> 2 blocks/CU = 16 waves/CU (4/SIMD).
// ---------------------------------------------------------------------------
template<bool PREP>
__global__ __launch_bounds__(512, 4) void fused_mlp(
  const float* __restrict__ points, const int* __restrict__ cats,
  const float* __restrict__ W1, const float* __restrict__ b1,
  const float* __restrict__ g1, const float* __restrict__ be1,
  const float* __restrict__ W2f, const float* __restrict__ b2,
  const float* __restrict__ g2, const float* __restrict__ be2,
  const float* __restrict__ W3, const float* __restrict__ b3,
  const unsigned short* __restrict__ W2s,
  float* __restrict__ out)
{
  __shared__ union SM {
    unsigned short h1[64 * 512];   // 64KB bf16 A-tile (XOR-swizzled rows)
    float h2[64 * 292];            // 74.75KB fp32 post-GEMM overlay
  } sm;

  const int t    = (int)threadIdx.x;
  const int lane = t & 63;
  const int w    = t >> 6;                 // wave id 0..7 (owns cols [32w,32w+32))
  const int bx   = (int)blockIdx.x;
  const int b    = bx >> 7;                // 128 tiles per batch
  const int n0   = (bx & 127) << 6;
  const int e    = cats[b];

  // --- B-fragment loader: 4 frags (2 sub x 2 n) for one K-chunk, to regs ---
  const int bcol  = w * 32 + (lane & 15);  // + n*16
  const int kslot = lane >> 4;
  auto loadB = [&](short8* dst, int kc){
    if(kc >= 8) return;
    #pragma unroll
    for(int sub = 0; sub < 2; sub++){
      #pragma unroll
      for(int n = 0; n < 2; n++){
        if constexpr (PREP){
          const unsigned short* p = W2s + (((size_t)(e * 8 + kc) * 2 + sub) << 13)
                                  + (((bcol + n * 16) << 5) + (kslot << 3));
          dst[sub * 2 + n] = *(const short8*)p;
        } else {
          const float* p = W2f + (((size_t)e * 512 + kc * 64 + sub * 32 + kslot * 8) << 8)
                         + (bcol + n * 16);
          short8 v;
          #pragma unroll
          for(int kk = 0; kk < 8; kk++) v[kk] = (short)f2bf(p[(size_t)kk << 8]);
          dst[sub * 2 + n] = v;
        }
      }
    }
  };

  short8 bA[4], bB[4];
  loadB(bA, 0);    // prefetch chunk 0; hides under Phase A

  // ---------------- Phase A: layer1 + LN1 + lrelu -> bf16 LDS ----------------
  {
    const int p = t >> 3, q = t & 7;       // 8 threads per point (same wave)
    const float* pp = points + (size_t)(b * NN + n0 + p) * 3;
    const float p0 = pp[0], p1 = pp[1], p2 = pp[2];
    const float* w1a = W1 + (size_t)e * 3 * NH;
    const float* w1b = w1a + NH;
    const float* w1c = w1b + NH;
    const float* b1e = b1 + (size_t)e * NH;
    short8 hr[8];                           // pre-LN h, bf16-packed (32 VGPR)
    float sum = 0.f, ssq = 0.f;
    #pragma unroll
    for(int j = 0; j < 8; j++){
      int c0 = q * 64 + j * 8;
      f32x4 a0 = *(const f32x4*)(w1a + c0), a1 = *(const f32x4*)(w1a + c0 + 4);
      f32x4 u0 = *(const f32x4*)(w1b + c0), u1 = *(const f32x4*)(w1b + c0 + 4);
      f32x4 d0 = *(const f32x4*)(w1c + c0), d1 = *(const f32x4*)(w1c + c0 + 4);
      f32x4 e0 = *(const f32x4*)(b1e + c0), e1 = *(const f32x4*)(b1e + c0 + 4);
      short8 pk;
      #pragma unroll
      for(int i = 0; i < 4; i++){
        float h = fmaf(p0, a0[i], fmaf(p1, u0[i], fmaf(p2, d0[i], e0[i])));
        sum += h; ssq = fmaf(h, h, ssq);
        pk[i] = (short)f2bf(h);
        float h2v = fmaf(p0, a1[i], fmaf(p1, u1[i], fmaf(p2, d1[i], e1[i])));
        sum += h2v; ssq = fmaf(h2v, h2v, ssq);
        pk[4 + i] = (short)f2bf(h2v);
      }
      hr[j] = pk;
    }
    sum += __shfl_xor(sum, 1); sum += __shfl_xor(sum, 2); sum += __shfl_xor(sum, 4);
    ssq += __shfl_xor(ssq, 1); ssq += __shfl_xor(ssq, 2); ssq += __shfl_xor(ssq, 4);
    float mu = sum * (1.f / NH);
    float rs = rsqrtf(fmaf(-mu, mu, ssq * (1.f / NH)) + HEPS);
    const float* g1e  = g1  + (size_t)e * NH;
    const float* be1e = be1 + (size_t)e * NH;
    #pragma unroll
    for(int j = 0; j < 8; j++){
      int c0 = q * 64 + j * 8;
      f32x4 gg0 = *(const f32x4*)(g1e + c0),  gg1 = *(const f32x4*)(g1e + c0 + 4);
      f32x4 ee0 = *(const f32x4*)(be1e + c0), ee1 = *(const f32x4*)(be1e + c0 + 4);
      short8 v = hr[j], pk;
      #pragma unroll
      for(int i = 0; i < 8; i++){
        float x = bf2f((unsigned short)v[i]);
        float gv = (i < 4) ? gg0[i] : gg1[i - 4];
        float bv = (i < 4) ? ee0[i] : ee1[i - 4];
        x = (x - mu) * rs;
        x = fmaf(x, gv, bv);
        x = (x >= 0.f) ? x : HSLOPE * x;
        pk[i] = (short)f2bf(x);
      }
      // row-XOR swizzle: bank-conflict-free for write and GEMM A-reads
      *(short8*)(sm.h1 + (((p << 9) + c0) ^ ((p & 7) << 3))) = pk;
    }
  }
  __syncthreads();   // h1 visible to all waves

  // ---------------- GEMM: barrier-free K-loop, 2-deep B prefetch ----------------
  f32x4 acc[4][2];
  #pragma unroll
  for(int m = 0; m < 4; m++)
    #pragma unroll
    for(int n = 0; n < 2; n++){ f32x4 z = {0.f,0.f,0.f,0.f}; acc[m][n] = z; }

  const int krow  = (lane >> 4) << 3;
  const int arow0 = lane & 15;
  auto compute = [&](int kc, short8* bf){
    #pragma unroll
    for(int sub = 0; sub < 2; sub++){
      short8 af[4];
      #pragma unroll
      for(int m = 0; m < 4; m++){
        int row = m * 16 + arow0;
        int hw = ((row << 9) + (kc << 6) + (sub << 5) + krow) ^ ((row & 7) << 3);
        af[m] = *(const short8*)(sm.h1 + hw);
      }
      #pragma unroll
      for(int m = 0; m < 4; m++)
        #pragma unroll
        for(int n = 0; n < 2; n++)
          acc[m][n] = __builtin_amdgcn_mfma_f32_16x16x32_bf16(af[m], bf[sub * 2 + n], acc[m][n], 0, 0, 0);
    }
  };

  #pragma unroll
  for(int kc2 = 0; kc2 < 4; kc2++){
    loadB(bB, kc2 * 2 + 1);
    compute(kc2 * 2, bA);
    loadB(bA, kc2 * 2 + 2);
    compute(kc2 * 2 + 1, bB);
  }

  __syncthreads();   // all waves done reading h1 before h2 overlay

  // ---------------- Epilogue: +b2 -> fp32 h2 overlay ----------------
  // word addr(row,col) = row*292 + (col>>6)*72 + (col&63); 292%32=4, 72%32=8
  // -> stores 2 lanes/bank (free), vector reads perfect 8-per-group.
  {
    const float* b2e = b2 + e * 256;
    #pragma unroll
    for(int n = 0; n < 2; n++){
      int col = w * 32 + n * 16 + (lane & 15);
      float bc = b2e[col];
      int cbase = (col >> 6) * 72 + (col & 63);
      #pragma unroll
      for(int m = 0; m < 4; m++){
        int row0 = m * 16 + ((lane >> 4) << 2);   // C/D: col=lane&15, row=(lane>>4)*4+r
        #pragma unroll
        for(int r = 0; r < 4; r++)
          sm.h2[(row0 + r) * 292 + cbase] = acc[m][n][r] + bc;
      }
    }
  }
  __syncthreads();

  // ---------------- LN2 + lrelu + layer3 (fully vectorized) ----------------
  {
    const int p = t >> 3, q = t & 7;          // thread owns cols [32q, 32q+32)
    const float* hrow = sm.h2 + p * 292 + (q >> 1) * 72 + (q & 1) * 32;
    float s = 0.f, sq = 0.f;
    f32x4 xs[8];
    #pragma unroll
    for(int j = 0; j < 8; j++){
      f32x4 v = *(const f32x4*)(hrow + j * 4);
      xs[j] = v;
      #pragma unroll
      for(int i = 0; i < 4; i++){ s += v[i]; sq = fmaf(v[i], v[i], sq); }
    }
    s  += __shfl_xor(s, 1);  s  += __shfl_xor(s, 2);  s  += __shfl_xor(s, 4);
    sq += __shfl_xor(sq, 1); sq += __shfl_xor(sq, 2); sq += __shfl_xor(sq, 4);
    float mu = s * (1.f / 256.f);
    float rs = rsqrtf(fmaf(-mu, mu, sq * (1.f / 256.f)) + HEPS);
    const float* g2e  = g2  + (size_t)e * 256 + q * 32;
    const float* be2e = be2 + (size_t)e * 256 + q * 32;
    const float* w3e  = W3 + ((size_t)e * 256 + q * 32) * 3;
    float o0 = 0.f, o1 = 0.f, o2 = 0.f;
    #pragma unroll
    for(int j = 0; j < 8; j++){
      f32x4 gg = *(const f32x4*)(g2e + j * 4);
      f32x4 bb = *(const f32x4*)(be2e + j * 4);
      f32x4 W0 = *(const f32x4*)(w3e + j * 12);
      f32x4 W1v = *(const f32x4*)(w3e + j * 12 + 4);
      f32x4 W2v = *(const f32x4*)(w3e + j * 12 + 8);
      f32x4 x = xs[j];
      #pragma unroll
      for(int i = 0; i < 4; i++){
        float xv = (x[i] - mu) * rs;
        xv = fmaf(xv, gg[i], bb[i]);
        x[i] = (xv >= 0.f) ? xv : HSLOPE * xv;
      }
      o0 = fmaf(x[0], W0[0], o0); o1 = fmaf(x[0], W0[1], o1); o2 = fmaf(x[0], W0[2], o2);
      o0 = fmaf(x[1], W0[3], o0); o1 = fmaf(x[1], W1v[0], o1); o2 = fmaf(x[1], W1v[1], o2);
      o0 = fmaf(x[2], W1v[2], o0); o1 = fmaf(x[2], W1v[3], o1); o2 = fmaf(x[2], W2v[0], o2);
      o0 = fmaf(x[3], W2v[1], o0); o1 = fmaf(x[3], W2v[2], o1); o2 = fmaf(x[3], W2v[3], o2);
    }
    o0 += __shfl_xor(o0, 1); o0 += __shfl_xor(o0, 2); o0 += __shfl_xor(o0, 4);
    o1 += __shfl_xor(o1, 1); o1 += __shfl_xor(o1, 2); o1 += __shfl_xor(o1, 4);
    o2 += __shfl_xor(o2, 1); o2 += __shfl_xor(o2, 2); o2 += __shfl_xor(o2, 4);
    if(q == 0){
      float* op = out + (size_t)(b * NN + n0 + p) * 3;
      op[0] = o0 + b3[e * 3 + 0];
      op[1] = o1 + b3[e * 3 + 1];
      op[2] = o2 + b3[e * 3 + 2];
    }
  }
}

extern "C" void kernel_launch(void* const* d_in, const int* in_sizes, int n_in,
                              void* d_out, int out_size, void* d_ws, size_t ws_size,
                              hipStream_t stream) {
  const float* points = (const float*)d_in[0];
  const int*   cats   = (const int*)d_in[1];
  const float* W1  = (const float*)d_in[2];
  const float* b1  = (const float*)d_in[3];
  const float* g1  = (const float*)d_in[4];
  const float* be1 = (const float*)d_in[5];
  const float* W2  = (const float*)d_in[6];
  const float* b2  = (const float*)d_in[7];
  const float* g2  = (const float*)d_in[8];
  const float* be2 = (const float*)d_in[9];
  const float* W3  = (const float*)d_in[10];
  const float* b3  = (const float*)d_in[11];
  float* out = (float*)d_out;

  const size_t ws_needed = (size_t)NE * 512 * 256 * 2;   // 2.62 MB bf16 W2 image
  if (ws_size >= ws_needed) {
    unsigned short* ws = (unsigned short*)d_ws;
    prep_w2<<<dim3((NE * 512 * 256) / 256), dim3(256), 0, stream>>>(W2, ws);
    fused_mlp<true><<<dim3(NB * (NN / 64)), dim3(512), 0, stream>>>(
        points, cats, W1, b1, g1, be1, W2, b2, g2, be2, W3, b3, ws, out);
  } else {
    fused_mlp<false><<<dim3(NB * (NN / 64)), dim3(512), 0, stream>>>(
        points, cats, W1, b1, g1, be1, W2, b2, g2, be2, W3, b3, nullptr, out);
  }
}

// Round 4
// 521.769 us; speedup vs baseline: 1.1268x; 1.1268x over previous
//
#include <hip/hip_runtime.h>
#include <stdint.h>
#include <stddef.h>

// Problem constants (fixed by reference)
#define NB 32
#define NN 8192
#define NH 512
#define NE 10
#define HEPS 1e-5f
#define HSLOPE 0.2f

typedef short short8 __attribute__((ext_vector_type(8)));
typedef float f32x4 __attribute__((ext_vector_type(4)));

static __device__ __forceinline__ unsigned short f2bf(float f){
  unsigned u = __float_as_uint(f);
  u += 0x7FFFu + ((u >> 16) & 1u);   // RNE
  return (unsigned short)(u >> 16);
}
static __device__ __forceinline__ float bf2f(unsigned short h){
  return __uint_as_float(((unsigned)h) << 16);
}

// ---------------------------------------------------------------------------
// Prep: W2 [E][512][256] f32 -> bf16 k-major fragment image in ws.
// Layout: [e][kc(8)][sub(2)][col(256)][kslot(4)][kk(8)] halfwords, so a wave's
// B-fragment (col = n*16 + lane&15, k = kc*64+sub*32+(lane>>4)*8+kk) is ONE
// fully-coalesced global_load_dwordx4 (64 lanes x 16B = contiguous 1KB).
// ---------------------------------------------------------------------------
__global__ __launch_bounds__(256) void prep_w2(const float* __restrict__ W2,
                                               unsigned short* __restrict__ ws){
  int idx = blockIdx.x * 256 + threadIdx.x;   // e*131072 + k*256 + col (coalesced read)
  int col = idx & 255;
  int k   = (idx >> 8) & 511;
  int e   = idx >> 17;
  int kc = k >> 6, sub = (k >> 5) & 1, kslot = (k >> 3) & 3, kk = k & 7;
  ws[(((size_t)(e * 8 + kc) * 2 + sub) << 13) + (col << 5) + (kslot << 3) + kk]
      = f2bf(W2[idx]);
}

// h2 LDS addressing: stride 256 words/row, 16B-block XOR swizzle.
// word(row,col) = (row<<8) + (((col>>2) ^ (row&7))<<2) + (col&3)
// Writer (C-frag scalar stores): every bank hit exactly 2x -> free.
// Reader (b128, thread q <- cols {32k+4q+i}): 8-lane groups' block idx mod 8
//   = q ^ (p&7), all distinct -> conflict-free.
static __device__ __forceinline__ int hw2(int row, int col){
  return (row << 8) + ((((col >> 2) ^ (row & 7)) << 2)) + (col & 3);
}

// ---------------------------------------------------------------------------
// Fused kernel: one block = 64 points, 8 waves (512 thr), 2 blocks/CU.
//   Phase A : layer1 fp32 (8 thr/point, h in regs) -> LN1 -> lrelu -> bf16 LDS
//   GEMM    : 64x256 = A(64x512 LDS) x W2(512x256, direct L2->reg loads),
//             mfma 16x16x32, barrier-free K-loop, 2-deep B prefetch,
//             wave w owns cols [32w, 32w+32)
//   Epilog  : +b2 -> fp32 h2 LDS (XOR-swizzled) -> vectorized LN2+lrelu+layer3
// LDS = 64KB (h1 and h2 overlay are both exactly 64KB) -> 2 blocks/CU.
// ---------------------------------------------------------------------------
template<bool PREP>
__global__ __launch_bounds__(512, 2) void fused_mlp(
  const float* __restrict__ points, const int* __restrict__ cats,
  const float* __restrict__ W1, const float* __restrict__ b1,
  const float* __restrict__ g1, const float* __restrict__ be1,
  const float* __restrict__ W2f, const float* __restrict__ b2,
  const float* __restrict__ g2, const float* __restrict__ be2,
  const float* __restrict__ W3, const float* __restrict__ b3,
  const unsigned short* __restrict__ W2s,
  float* __restrict__ out)
{
  __shared__ union SM {
    unsigned short h1[64 * 512];   // 64KB bf16 A-tile (XOR-swizzled rows)
    float h2[64 * 256];            // 64KB fp32 post-GEMM overlay (XOR-swizzled)
  } sm;

  const int t    = (int)threadIdx.x;
  const int lane = t & 63;
  const int w    = t >> 6;                 // wave id 0..7 (owns cols [32w,32w+32))
  const int bx   = (int)blockIdx.x;
  const int b    = bx >> 7;                // 128 tiles per batch
  const int n0   = (bx & 127) << 6;
  const int e    = cats[b];

  // --- B-fragment loader: 4 frags (2 sub x 2 n) for one K-chunk, to regs ---
  const int bcol  = w * 32 + (lane & 15);  // + n*16
  const int kslot = lane >> 4;
  auto loadB = [&](short8* dst, int kc){
    if(kc >= 8) return;
    #pragma unroll
    for(int sub = 0; sub < 2; sub++){
      #pragma unroll
      for(int n = 0; n < 2; n++){
        if constexpr (PREP){
          const unsigned short* p = W2s + (((size_t)(e * 8 + kc) * 2 + sub) << 13)
                                  + (((bcol + n * 16) << 5) + (kslot << 3));
          dst[sub * 2 + n] = *(const short8*)p;
        } else {
          const float* p = W2f + (((size_t)e * 512 + kc * 64 + sub * 32 + kslot * 8) << 8)
                         + (bcol + n * 16);
          short8 v;
          #pragma unroll
          for(int kk = 0; kk < 8; kk++) v[kk] = (short)f2bf(p[(size_t)kk << 8]);
          dst[sub * 2 + n] = v;
        }
      }
    }
  };

  short8 bA[4], bB[4];
  loadB(bA, 0);    // prefetch chunk 0; hides under Phase A

  // ---------------- Phase A: layer1 + LN1 + lrelu -> bf16 LDS ----------------
  {
    const int p = t >> 3, q = t & 7;       // 8 threads per point (same wave)
    const float* pp = points + (size_t)(b * NN + n0 + p) * 3;
    const float p0 = pp[0], p1 = pp[1], p2 = pp[2];
    const float* w1a = W1 + (size_t)e * 3 * NH;
    const float* w1b = w1a + NH;
    const float* w1c = w1b + NH;
    const float* b1e = b1 + (size_t)e * NH;
    short8 hr[8];                           // pre-LN h, bf16-packed (32 VGPR)
    float sum = 0.f, ssq = 0.f;
    #pragma unroll
    for(int j = 0; j < 8; j++){
      int c0 = q * 64 + j * 8;
      f32x4 a0 = *(const f32x4*)(w1a + c0), a1 = *(const f32x4*)(w1a + c0 + 4);
      f32x4 u0 = *(const f32x4*)(w1b + c0), u1 = *(const f32x4*)(w1b + c0 + 4);
      f32x4 d0 = *(const f32x4*)(w1c + c0), d1 = *(const f32x4*)(w1c + c0 + 4);
      f32x4 e0 = *(const f32x4*)(b1e + c0), e1 = *(const f32x4*)(b1e + c0 + 4);
      short8 pk;
      #pragma unroll
      for(int i = 0; i < 4; i++){
        float h = fmaf(p0, a0[i], fmaf(p1, u0[i], fmaf(p2, d0[i], e0[i])));
        sum += h; ssq = fmaf(h, h, ssq);
        pk[i] = (short)f2bf(h);
        float h2v = fmaf(p0, a1[i], fmaf(p1, u1[i], fmaf(p2, d1[i], e1[i])));
        sum += h2v; ssq = fmaf(h2v, h2v, ssq);
        pk[4 + i] = (short)f2bf(h2v);
      }
      hr[j] = pk;
    }
    sum += __shfl_xor(sum, 1); sum += __shfl_xor(sum, 2); sum += __shfl_xor(sum, 4);
    ssq += __shfl_xor(ssq, 1); ssq += __shfl_xor(ssq, 2); ssq += __shfl_xor(ssq, 4);
    float mu = sum * (1.f / NH);
    float rs = rsqrtf(fmaf(-mu, mu, ssq * (1.f / NH)) + HEPS);
    const float* g1e  = g1  + (size_t)e * NH;
    const float* be1e = be1 + (size_t)e * NH;
    #pragma unroll
    for(int j = 0; j < 8; j++){
      int c0 = q * 64 + j * 8;
      f32x4 gg0 = *(const f32x4*)(g1e + c0),  gg1 = *(const f32x4*)(g1e + c0 + 4);
      f32x4 ee0 = *(const f32x4*)(be1e + c0), ee1 = *(const f32x4*)(be1e + c0 + 4);
      short8 v = hr[j], pk;
      #pragma unroll
      for(int i = 0; i < 8; i++){
        float x = bf2f((unsigned short)v[i]);
        float gv = (i < 4) ? gg0[i] : gg1[i - 4];
        float bv = (i < 4) ? ee0[i] : ee1[i - 4];
        x = (x - mu) * rs;
        x = fmaf(x, gv, bv);
        x = (x >= 0.f) ? x : HSLOPE * x;
        pk[i] = (short)f2bf(x);
      }
      // row-XOR swizzle: bank-conflict-free for write and GEMM A-reads
      *(short8*)(sm.h1 + (((p << 9) + c0) ^ ((p & 7) << 3))) = pk;
    }
  }
  __syncthreads();   // h1 visible to all waves

  // ---------------- GEMM: barrier-free K-loop, 2-deep B prefetch ----------------
  f32x4 acc[4][2];
  #pragma unroll
  for(int m = 0; m < 4; m++)
    #pragma unroll
    for(int n = 0; n < 2; n++){ f32x4 z = {0.f,0.f,0.f,0.f}; acc[m][n] = z; }

  const int krow  = (lane >> 4) << 3;
  const int arow0 = lane & 15;
  auto compute = [&](int kc, short8* bf){
    #pragma unroll
    for(int sub = 0; sub < 2; sub++){
      short8 af[4];
      #pragma unroll
      for(int m = 0; m < 4; m++){
        int row = m * 16 + arow0;
        int hw = ((row << 9) + (kc << 6) + (sub << 5) + krow) ^ ((row & 7) << 3);
        af[m] = *(const short8*)(sm.h1 + hw);
      }
      #pragma unroll
      for(int m = 0; m < 4; m++)
        #pragma unroll
        for(int n = 0; n < 2; n++)
          acc[m][n] = __builtin_amdgcn_mfma_f32_16x16x32_bf16(af[m], bf[sub * 2 + n], acc[m][n], 0, 0, 0);
    }
  };

  #pragma unroll
  for(int kc2 = 0; kc2 < 4; kc2++){
    loadB(bB, kc2 * 2 + 1);
    compute(kc2 * 2, bA);
    loadB(bA, kc2 * 2 + 2);
    compute(kc2 * 2 + 1, bB);
  }

  __syncthreads();   // all waves done reading h1 before h2 overlay

  // ---------------- Epilogue: +b2 -> fp32 h2 overlay (swizzled) ----------------
  {
    const float* b2e = b2 + e * 256;
    #pragma unroll
    for(int n = 0; n < 2; n++){
      int col = w * 32 + n * 16 + (lane & 15);
      float bc = b2e[col];
      #pragma unroll
      for(int m = 0; m < 4; m++){
        int row0 = m * 16 + ((lane >> 4) << 2);   // C/D: col=lane&15, row=(lane>>4)*4+r
        #pragma unroll
        for(int r = 0; r < 4; r++)
          sm.h2[hw2(row0 + r, col)] = acc[m][n][r] + bc;
      }
    }
  }
  __syncthreads();

  // ---------------- LN2 + lrelu + layer3 (vectorized, conflict-free) ----------------
  {
    const int p = t >> 3, q = t & 7;          // thread owns cols {32k+4q+i}
    const float* h2base = sm.h2 + (p << 8);
    const int px = p & 7;
    float s = 0.f, sq = 0.f;
    f32x4 xs[8];
    #pragma unroll
    for(int k = 0; k < 8; k++){
      f32x4 v = *(const f32x4*)(h2base + (((8 * k + q) ^ px) << 2));
      xs[k] = v;
      #pragma unroll
      for(int i = 0; i < 4; i++){ s += v[i]; sq = fmaf(v[i], v[i], sq); }
    }
    s  += __shfl_xor(s, 1);  s  += __shfl_xor(s, 2);  s  += __shfl_xor(s, 4);
    sq += __shfl_xor(sq, 1); sq += __shfl_xor(sq, 2); sq += __shfl_xor(sq, 4);
    float mu = s * (1.f / 256.f);
    float rs = rsqrtf(fmaf(-mu, mu, sq * (1.f / 256.f)) + HEPS);
    const float* g2e  = g2  + (size_t)e * 256 + q * 4;
    const float* be2e = be2 + (size_t)e * 256 + q * 4;
    const float* w3e  = W3 + ((size_t)e * 256 + q * 4) * 3;
    float o0 = 0.f, o1 = 0.f, o2 = 0.f;
    #pragma unroll
    for(int k = 0; k < 8; k++){
      f32x4 gg = *(const f32x4*)(g2e + k * 32);
      f32x4 bb = *(const f32x4*)(be2e + k * 32);
      f32x4 W0  = *(const f32x4*)(w3e + k * 96);
      f32x4 W1v = *(const f32x4*)(w3e + k * 96 + 4);
      f32x4 W2v = *(const f32x4*)(w3e + k * 96 + 8);
      f32x4 x = xs[k];
      #pragma unroll
      for(int i = 0; i < 4; i++){
        float xv = (x[i] - mu) * rs;
        xv = fmaf(xv, gg[i], bb[i]);
        x[i] = (xv >= 0.f) ? xv : HSLOPE * xv;
      }
      o0 = fmaf(x[0], W0[0], o0); o1 = fmaf(x[0], W0[1], o1); o2 = fmaf(x[0], W0[2], o2);
      o0 = fmaf(x[1], W0[3], o0); o1 = fmaf(x[1], W1v[0], o1); o2 = fmaf(x[1], W1v[1], o2);
      o0 = fmaf(x[2], W1v[2], o0); o1 = fmaf(x[2], W1v[3], o1); o2 = fmaf(x[2], W2v[0], o2);
      o0 = fmaf(x[3], W2v[1], o0); o1 = fmaf(x[3], W2v[2], o1); o2 = fmaf(x[3], W2v[3], o2);
    }
    o0 += __shfl_xor(o0, 1); o0 += __shfl_xor(o0, 2); o0 += __shfl_xor(o0, 4);
    o1 += __shfl_xor(o1, 1); o1 += __shfl_xor(o1, 2); o1 += __shfl_xor(o1, 4);
    o2 += __shfl_xor(o2, 1); o2 += __shfl_xor(o2, 2); o2 += __shfl_xor(o2, 4);
    if(q == 0){
      float* op = out + (size_t)(b * NN + n0 + p) * 3;
      op[0] = o0 + b3[e * 3 + 0];
      op[1] = o1 + b3[e * 3 + 1];
      op[2] = o2 + b3[e * 3 + 2];
    }
  }
}

extern "C" void kernel_launch(void* const* d_in, const int* in_sizes, int n_in,
                              void* d_out, int out_size, void* d_ws, size_t ws_size,
                              hipStream_t stream) {
  const float* points = (const float*)d_in[0];
  const int*   cats   = (const int*)d_in[1];
  const float* W1  = (const float*)d_in[2];
  const float* b1  = (const float*)d_in[3];
  const float* g1  = (const float*)d_in[4];
  const float* be1 = (const float*)d_in[5];
  const float* W2  = (const float*)d_in[6];
  const float* b2  = (const float*)d_in[7];
  const float* g2  = (const float*)d_in[8];
  const float* be2 = (const float*)d_in[9];
  const float* W3  = (const float*)d_in[10];
  const float* b3  = (const float*)d_in[11];
  float* out = (float*)d_out;

  const size_t ws_needed = (size_t)NE * 512 * 256 * 2;   // 2.62 MB bf16 W2 image
  if (ws_size >= ws_needed) {
    unsigned short* ws = (unsigned short*)d_ws;
    prep_w2<<<dim3((NE * 512 * 256) / 256), dim3(256), 0, stream>>>(W2, ws);
    fused_mlp<true><<<dim3(NB * (NN / 64)), dim3(512), 0, stream>>>(
        points, cats, W1, b1, g1, be1, W2, b2, g2, be2, W3, b3, ws, out);
  } else {
    fused_mlp<false><<<dim3(NB * (NN / 64)), dim3(512), 0, stream>>>(
        points, cats, W1, b1, g1, be1, W2, b2, g2, be2, W3, b3, nullptr, out);
  }
}